// Round 7
// baseline (551.829 us; speedup 1.0000x reference)
//
#include <hip/hip_runtime.h>
#include <limits.h>

// USR_EMB: out[b,h,:] = emb_usr[searchsorted(userlist, x[b,h]), :]
// EMB = 64 floats = 16 float4 = 256 B per row. Table = 100001 rows = 25.6 MB.
//
// R11: XCD partition with the mapping VERIFIED BY CONSTRUCTION.
//   R7-R10 (all null) assumed blockIdx%8 -> XCD round-robin. If that
//   assumption is false for this grid, the partition never ran. Now each
//   block reads its REAL XCD id from hwreg 20 (HW_REG_XCC_ID, gfx940+),
//   and claims 2048-element chunks from per-id-range atomic queues in d_ws:
//     - first its own XCD's range (gathers hit the 3.2 MB slice pinned in
//       the local 4 MB L2),
//     - then steals from other ranges (correctness never depends on the
//       hardware mapping or dispatch balance; only locality does).
//   Every (range, chunk) pair is claimed exactly once via device-scope
//   atomicAdd. Queues are zeroed by a capture-safe hipMemsetAsync.
//   All R10 cache discipline kept: nt sc0 sc1 streaming stores (no L2
//   write-allocate), nt sc0 sc1 x loads (no read-once allocation), range
//   test by two scalar compares (total searchsorted probes = n_elem).

#define V4_PER_ROW 16       // 64 floats / 4
#define ELEMS_PER_BLOCK 2048
#define NXCD 8

typedef float f32x4 __attribute__((ext_vector_type(4)));
typedef int   i32x4 __attribute__((ext_vector_type(4)));

__device__ __forceinline__ void store_stream_f4(f32x4* p, f32x4 v)
{
    // Non-temporal, no L2 allocation: output stream can't evict the slice.
    asm volatile("global_store_dwordx4 %0, %1, off nt sc0 sc1"
                 :
                 : "v"(p), "v"(v));
}

__device__ __forceinline__ i32x4 load_stream_i4(const int* p)
{
    // Read-once x data: no L2 allocation. waitcnt inside the asm because the
    // compiler can't track an asm load's completion. 2 per chunk: negligible.
    i32x4 r;
    asm volatile("global_load_dwordx4 %0, %1, off nt sc0 sc1\n\t"
                 "s_waitcnt vmcnt(0)"
                 : "=v"(r)
                 : "v"(p));
    return r;
}

__device__ __forceinline__ int get_xcc_id()
{
    // hwreg id 20 = HW_REG_XCC_ID (gfx940+; learn_hip m09-verified probe).
    // Masked to 0..7; if the read were ever wrong, work-stealing still
    // guarantees correctness — only locality would degrade.
    int v;
    asm("s_getreg_b32 %0, hwreg(20, 0, 32)" : "=s"(v));
    return v & (NXCD - 1);
}

__global__ __launch_bounds__(256) void usr_emb_gather(
    const int* __restrict__ x,
    const int* __restrict__ userlist, int n_user,
    const float* __restrict__ emb,
    float* __restrict__ out,
    int n_elem, int n_chunks,
    int* __restrict__ claim)          // [NXCD] chunk counters, pre-zeroed
{
    __shared__ int q_id[ELEMS_PER_BLOCK];
    __shared__ int q_ge[ELEMS_PER_BLOCK];
    __shared__ int q_count;
    __shared__ int s_j;

    const int t    = threadIdx.x;
    const int lane = t & 63;
    const int wave = t >> 6;

    const int xcd = get_xcc_id();             // block-uniform
    const int rs  = (n_user + NXCD - 1) >> 3; // ids per range

    const f32x4* __restrict__ emb4 = (const f32x4*)emb;
    f32x4*       __restrict__ out4 = (f32x4*)out;
    const int sub   = lane & (V4_PER_ROW - 1);
    const int eslot = lane >> 4;

    const int v1 = userlist[1];               // for the interpolation probe

    // Own range first, then steal from the others.
    for (int cc = 0; cc < NXCD; ++cc) {
        const int c     = (xcd + cc) & (NXCD - 1);
        const int lo_id = c * rs;
        const int hi_id = min(lo_id + rs, n_user);
        // Range test without searchsorted:
        //   id >= lo_id <=> u > userlist[lo_id-1]; id < hi_id <=> u <= userlist[hi_id-1]
        const int ul_lo = (lo_id > 0) ? userlist[lo_id - 1] : INT_MIN;
        const int ul_hi = userlist[hi_id - 1];

        for (;;) {
            if (t == 0) {
                s_j     = atomicAdd(&claim[c], 1);   // device-scope: cross-XCD safe
                q_count = 0;
            }
            __syncthreads();
            const int j = s_j;
            if (j >= n_chunks) break;
            const int e0 = j * ELEMS_PER_BLOCK;

            // ---- Phase A: scan chunk, queue in-range elements ----
#pragma unroll
            for (int r = 0; r < 2; ++r) {
                const int base = e0 + r * 1024 + t * 4;
                int  u[4];
                bool valid[4];
                if (base + 3 < n_elem) {
                    const i32x4 xv = load_stream_i4(x + base);
                    u[0] = xv.x; u[1] = xv.y; u[2] = xv.z; u[3] = xv.w;
                    valid[0] = valid[1] = valid[2] = valid[3] = true;
                } else {
#pragma unroll
                    for (int k = 0; k < 4; ++k) {
                        valid[k] = (base + k) < n_elem;
                        u[k]     = valid[k] ? x[base + k] : 0;
                    }
                }
#pragma unroll
                for (int k = 0; k < 4; ++k) {
                    const bool flag = valid[k]
                                      && (lo_id == 0 || u[k] > ul_lo)
                                      && (u[k] <= ul_hi);
                    int id = 0;
                    if (flag) {                              // probe only in-range
                        int g = 1 + (u[k] - v1);             // interpolation probe
                        bool hit = (g >= 1 && g < n_user) && (userlist[g] == u[k]);
                        if (!hit) {                          // lower_bound fallback
                            int lo = 0, hi = n_user;
                            while (lo < hi) {
                                const int mid = (lo + hi) >> 1;
                                if (userlist[mid] < u[k]) lo = mid + 1;
                                else                      hi = mid;
                            }
                            g = lo;
                        }
                        id = g;
                    }
                    const unsigned long long m = __ballot(flag);
                    if (m) {
                        int pos = 0;
                        if (lane == 0) pos = atomicAdd(&q_count, __popcll(m));
                        pos = __shfl(pos, 0);
                        pos += __popcll(m & ((1ull << lane) - 1ull));
                        if (flag) {
                            q_id[pos] = id;
                            q_ge[pos] = base + k;
                        }
                    }
                }
            }
            __syncthreads();

            // ---- Phase B: wave-cooperative row copy (16 lanes / 256 B row) ----
            const int count = q_count;
            for (int i = wave * 4 + eslot; i < count; i += 16) {
                const int id = q_id[i];
                const int ge = q_ge[i];
                const f32x4 row = emb4[(size_t)id * V4_PER_ROW + sub];
                store_stream_f4(&out4[(size_t)ge * V4_PER_ROW + sub], row);
            }
            __syncthreads();   // LDS reuse safety before next claim
        }
        __syncthreads();       // all threads past s_j before next range reuses it
    }
}

extern "C" void kernel_launch(void* const* d_in, const int* in_sizes, int n_in,
                              void* d_out, int out_size, void* d_ws, size_t ws_size,
                              hipStream_t stream) {
    const int*   x        = (const int*)d_in[0];    // [BATCH*HIST] indices
    const int*   userlist = (const int*)d_in[1];    // [USR_SIZE+1] sorted ids
    const float* emb      = (const float*)d_in[2];  // [USR_SIZE+1, 64]
    float*       out      = (float*)d_out;          // [BATCH*HIST, 64]

    const int n_elem = in_sizes[0];                 // 819200
    const int n_user = in_sizes[1];                 // 100001

    const int chunks = (n_elem + ELEMS_PER_BLOCK - 1) / ELEMS_PER_BLOCK;  // 400
    const int blocks = chunks * NXCD;                                     // 3200

    // Zero the per-range claim counters (capture-safe async op on stream).
    hipMemsetAsync(d_ws, 0, NXCD * sizeof(int), stream);
    usr_emb_gather<<<blocks, 256, 0, stream>>>(x, userlist, n_user, emb, out,
                                               n_elem, chunks, (int*)d_ws);
}

// Round 8
// 279.100 us; speedup vs baseline: 1.9772x; 1.9772x over previous
//
#include <hip/hip_runtime.h>
#include <limits.h>

// USR_EMB: out[b,h,:] = emb_usr[searchsorted(userlist, x[b,h]), :]
// EMB = 64 floats = 16 float4 = 256 B per row. Table = 100001 rows = 25.6 MB.
//
// R12: R11 proved the XCD-locality program WORKS (FETCH_SIZE collapsed to
//   28 MB = compulsory minimum; writes exactly 210 MB) but ran 3x slower
//   (366 us, 8% HBM, VALUBusy 2.5%): all 8 claim counters sat in ONE 64 B
//   line -> one L2 slice serialized ~28,800 device-scope atomics (~30 cy
//   each ~= 360 us = the whole kernel), and every block WAITS on its claim.
//   Fixes, keeping the proven gather/store structure byte-identical:
//   (1) counters padded 256 B apart -> 8 slices service in parallel;
//   (2) atomics only on the OWN XCD's counter (~800/counter, home slice);
//       foreign ranges guarded by a plain load — counter is monotonic, so
//       a stale read is safe: >=n_chunks => truly exhausted (skip);
//       <n_chunks => do the atomic and learn the truth;
//   (3) the two x nt-loads issue back-to-back in one asm block with a
//       single s_waitcnt (one latency stall per chunk, not two).
//
// Cache discipline (unchanged, R11-proven): nt sc0 sc1 streaming stores
// (no L2 write-allocate), nt sc0 sc1 x loads (read-once, no allocation),
// gathers from the XCD-local 3.2 MB slice hit the 4 MB L2; range test via
// two wave-uniform scalar compares (total searchsorted probes = n_elem).

#define V4_PER_ROW 16       // 64 floats / 4
#define ELEMS_PER_BLOCK 2048
#define NXCD 8
#define CLAIM_STRIDE 64     // ints: 256 B between counters -> distinct L2 slices

typedef float f32x4 __attribute__((ext_vector_type(4)));
typedef int   i32x4 __attribute__((ext_vector_type(4)));

__device__ __forceinline__ void store_stream_f4(f32x4* p, f32x4 v)
{
    // Non-temporal, no L2 allocation: output stream can't evict the slice.
    asm volatile("global_store_dwordx4 %0, %1, off nt sc0 sc1"
                 :
                 : "v"(p), "v"(v));
}

__device__ __forceinline__ void load_stream_2xi4(const int* p0, const int* p1,
                                                 i32x4& a, i32x4& b)
{
    // Both chunk-halves in flight before ONE waitcnt: single latency stall.
    // Early-clobber outputs: first load writes %0 while %3 is still needed.
    asm volatile("global_load_dwordx4 %0, %2, off nt sc0 sc1\n\t"
                 "global_load_dwordx4 %1, %3, off nt sc0 sc1\n\t"
                 "s_waitcnt vmcnt(0)"
                 : "=&v"(a), "=&v"(b)
                 : "v"(p0), "v"(p1));
}

__device__ __forceinline__ int get_xcc_id()
{
    // hwreg id 20 = HW_REG_XCC_ID (gfx940+). Masked to 0..7; if ever wrong,
    // the claim queues still guarantee correctness — only locality degrades.
    int v;
    asm("s_getreg_b32 %0, hwreg(20, 0, 32)" : "=s"(v));
    return v & (NXCD - 1);
}

__global__ __launch_bounds__(256) void usr_emb_gather(
    const int* __restrict__ x,
    const int* __restrict__ userlist, int n_user,
    const float* __restrict__ emb,
    float* __restrict__ out,
    int n_elem, int n_chunks,
    int* __restrict__ claim)          // [NXCD*CLAIM_STRIDE], pre-zeroed
{
    __shared__ int q_id[ELEMS_PER_BLOCK];
    __shared__ int q_ge[ELEMS_PER_BLOCK];
    __shared__ int q_count;
    __shared__ int s_j;
    __shared__ int s_skip;

    const int t    = threadIdx.x;
    const int lane = t & 63;
    const int wave = t >> 6;

    const int xcd = get_xcc_id();             // block-uniform
    const int rs  = (n_user + NXCD - 1) >> 3; // ids per range

    const f32x4* __restrict__ emb4 = (const f32x4*)emb;
    f32x4*       __restrict__ out4 = (f32x4*)out;
    const int sub   = lane & (V4_PER_ROW - 1);
    const int eslot = lane >> 4;

    const int v1 = userlist[1];               // for the interpolation probe

    // Own range first (atomic-claimed), then foreign ranges (guarded steal).
    for (int cc = 0; cc < NXCD; ++cc) {
        const int c     = (xcd + cc) & (NXCD - 1);
        const int lo_id = c * rs;
        if (lo_id >= n_user) continue;
        const int hi_id = min(lo_id + rs, n_user);
        // id >= lo_id <=> u > userlist[lo_id-1]; id < hi_id <=> u <= userlist[hi_id-1]
        const int ul_lo = (lo_id > 0) ? userlist[lo_id - 1] : INT_MIN;
        const int ul_hi = userlist[hi_id - 1];

        if (cc > 0) {
            // Monotonic counter: stale-low just causes a harmless atomic;
            // read >= n_chunks can only under-report => truly exhausted.
            if (t == 0) s_skip = (*(volatile int*)&claim[c * CLAIM_STRIDE] >= n_chunks);
            __syncthreads();
            const int skip = s_skip;
            __syncthreads();          // all reads done before next write
            if (skip) continue;
        }

        for (;;) {
            if (t == 0) {
                s_j     = atomicAdd(&claim[c * CLAIM_STRIDE], 1);
                q_count = 0;
            }
            __syncthreads();
            const int j = s_j;        // block-uniform
            if (j >= n_chunks) break; // uniform break; post-loop barrier orders s_j
            const int e0 = j * ELEMS_PER_BLOCK;

            // ---- Phase A: scan chunk, queue in-range elements ----
            const int b0 = e0 + t * 4;          // elements [e0,     e0+1024)
            const int b1 = e0 + 1024 + t * 4;   // elements [e0+1024, e0+2048)
            int  u[8];
            bool valid[8];
            if (e0 + ELEMS_PER_BLOCK <= n_elem) {
                i32x4 xa, xb;
                load_stream_2xi4(x + b0, x + b1, xa, xb);
                u[0] = xa.x; u[1] = xa.y; u[2] = xa.z; u[3] = xa.w;
                u[4] = xb.x; u[5] = xb.y; u[6] = xb.z; u[7] = xb.w;
#pragma unroll
                for (int k = 0; k < 8; ++k) valid[k] = true;
            } else {
#pragma unroll
                for (int k = 0; k < 4; ++k) {
                    valid[k]     = (b0 + k) < n_elem;
                    u[k]         = valid[k]     ? x[b0 + k] : 0;
                    valid[4 + k] = (b1 + k) < n_elem;
                    u[4 + k]     = valid[4 + k] ? x[b1 + k] : 0;
                }
            }
#pragma unroll
            for (int k = 0; k < 8; ++k) {
                const int  ge   = (k < 4) ? (b0 + k) : (b1 + k - 4);
                const bool flag = valid[k]
                                  && (lo_id == 0 || u[k] > ul_lo)
                                  && (u[k] <= ul_hi);
                int id = 0;
                if (flag) {                              // probe only in-range
                    int g = 1 + (u[k] - v1);             // interpolation probe
                    bool hit = (g >= 1 && g < n_user) && (userlist[g] == u[k]);
                    if (!hit) {                          // lower_bound fallback
                        int lo = 0, hi = n_user;
                        while (lo < hi) {
                            const int mid = (lo + hi) >> 1;
                            if (userlist[mid] < u[k]) lo = mid + 1;
                            else                      hi = mid;
                        }
                        g = lo;
                    }
                    id = g;
                }
                const unsigned long long m = __ballot(flag);
                if (m) {
                    int pos = 0;
                    if (lane == 0) pos = atomicAdd(&q_count, __popcll(m));
                    pos = __shfl(pos, 0);
                    pos += __popcll(m & ((1ull << lane) - 1ull));
                    if (flag) {
                        q_id[pos] = id;
                        q_ge[pos] = ge;
                    }
                }
            }
            __syncthreads();

            // ---- Phase B: wave-cooperative row copy (16 lanes / 256 B row) ----
            const int count = q_count;
            for (int i = wave * 4 + eslot; i < count; i += 16) {
                const int id = q_id[i];
                const int ge = q_ge[i];
                const f32x4 row = emb4[(size_t)id * V4_PER_ROW + sub];
                store_stream_f4(&out4[(size_t)ge * V4_PER_ROW + sub], row);
            }
            __syncthreads();   // LDS + s_j reuse safety before next claim
        }
        __syncthreads();       // orders last s_j read before next range writes
    }
}

extern "C" void kernel_launch(void* const* d_in, const int* in_sizes, int n_in,
                              void* d_out, int out_size, void* d_ws, size_t ws_size,
                              hipStream_t stream) {
    const int*   x        = (const int*)d_in[0];    // [BATCH*HIST] indices
    const int*   userlist = (const int*)d_in[1];    // [USR_SIZE+1] sorted ids
    const float* emb      = (const float*)d_in[2];  // [USR_SIZE+1, 64]
    float*       out      = (float*)d_out;          // [BATCH*HIST, 64]

    const int n_elem = in_sizes[0];                 // 819200
    const int n_user = in_sizes[1];                 // 100001

    const int chunks = (n_elem + ELEMS_PER_BLOCK - 1) / ELEMS_PER_BLOCK;  // 400
    const int blocks = chunks * NXCD;                                     // 3200

    // Zero the padded claim counters (capture-safe async op on stream).
    hipMemsetAsync(d_ws, 0, NXCD * CLAIM_STRIDE * sizeof(int), stream);
    usr_emb_gather<<<blocks, 256, 0, stream>>>(x, userlist, n_user, emb, out,
                                               n_elem, chunks, (int*)d_ws);
}

// Round 9
// 276.044 us; speedup vs baseline: 1.9991x; 1.0111x over previous
//
#include <hip/hip_runtime.h>
#include <limits.h>

// USR_EMB: out[b,h,:] = emb_usr[searchsorted(userlist, x[b,h]), :]
// EMB = 64 floats = 16 float4 = 256 B per row. Table = 100001 rows = 25.6 MB.
//
// R13: R12 (XCC_ID partition + padded claims) PROVED fetch collapses to the
//   28 MB compulsory minimum, but ran ~149 us vs ~123 baseline => read
//   traffic was never the time wall. New suspect, by elimination + magnitude:
//   the `nt sc0 sc1` (system-scope, L2-bypassing) stores move 210 MB at
//   ~1.4 TB/s => ~145 us ~= the whole kernel. The fill kernel does 839 MB of
//   NORMAL stores in ~128 us (6.5 TB/s).
//   Deltas vs R12 (everything else byte-identical):
//   (1) stores are `nt` ONLY: through L2 (full write rate) with non-temporal
//       LRU hint, so write lines evict before the pinned table slice;
//   (2) Phase B processes 4 queue entries per lane per iteration with
//       independent gather loads -> MLP 1 -> 4 (runtime `count` had killed
//       unrolling; each lane ran a serial load->store chain).
//
// Kept from R11/R12: real XCD id from hwreg 20 (HW_REG_XCC_ID); per-range
// claim counters padded 256 B apart in d_ws (atomic only on own range,
// plain-load guard on foreign ranges — monotonic counter makes stale reads
// safe); nt sc0 sc1 x loads (read-once, no L2 allocation); range test via
// two wave-uniform scalar compares (total searchsorted probes = n_elem).

#define V4_PER_ROW 16       // 64 floats / 4
#define ELEMS_PER_BLOCK 2048
#define NXCD 8
#define CLAIM_STRIDE 64     // ints: 256 B between counters -> distinct L2 slices

typedef float f32x4 __attribute__((ext_vector_type(4)));
typedef int   i32x4 __attribute__((ext_vector_type(4)));

__device__ __forceinline__ void store_nt_f4(f32x4* p, f32x4 v)
{
    // nt ONLY: allocate in L2 at full write throughput, but mark the line
    // non-temporal so it is evicted before the table slice.
    asm volatile("global_store_dwordx4 %0, %1, off nt"
                 :
                 : "v"(p), "v"(v));
}

__device__ __forceinline__ void load_stream_2xi4(const int* p0, const int* p1,
                                                 i32x4& a, i32x4& b)
{
    // Both chunk-halves in flight before ONE waitcnt: single latency stall.
    asm volatile("global_load_dwordx4 %0, %2, off nt sc0 sc1\n\t"
                 "global_load_dwordx4 %1, %3, off nt sc0 sc1\n\t"
                 "s_waitcnt vmcnt(0)"
                 : "=&v"(a), "=&v"(b)
                 : "v"(p0), "v"(p1));
}

__device__ __forceinline__ int get_xcc_id()
{
    // hwreg id 20 = HW_REG_XCC_ID (gfx940+). Masked to 0..7; if ever wrong,
    // the claim queues still guarantee correctness — only locality degrades.
    int v;
    asm("s_getreg_b32 %0, hwreg(20, 0, 32)" : "=s"(v));
    return v & (NXCD - 1);
}

__global__ __launch_bounds__(256) void usr_emb_gather(
    const int* __restrict__ x,
    const int* __restrict__ userlist, int n_user,
    const float* __restrict__ emb,
    float* __restrict__ out,
    int n_elem, int n_chunks,
    int* __restrict__ claim)          // [NXCD*CLAIM_STRIDE], pre-zeroed
{
    __shared__ int q_id[ELEMS_PER_BLOCK];
    __shared__ int q_ge[ELEMS_PER_BLOCK];
    __shared__ int q_count;
    __shared__ int s_j;
    __shared__ int s_skip;

    const int t    = threadIdx.x;
    const int lane = t & 63;
    const int wave = t >> 6;

    const int xcd = get_xcc_id();             // block-uniform
    const int rs  = (n_user + NXCD - 1) >> 3; // ids per range

    const f32x4* __restrict__ emb4 = (const f32x4*)emb;
    f32x4*       __restrict__ out4 = (f32x4*)out;
    const int sub   = lane & (V4_PER_ROW - 1);
    const int eslot = lane >> 4;

    const int v1 = userlist[1];               // for the interpolation probe

    // Own range first (atomic-claimed), then foreign ranges (guarded steal).
    for (int cc = 0; cc < NXCD; ++cc) {
        const int c     = (xcd + cc) & (NXCD - 1);
        const int lo_id = c * rs;
        if (lo_id >= n_user) continue;
        const int hi_id = min(lo_id + rs, n_user);
        // id >= lo_id <=> u > userlist[lo_id-1]; id < hi_id <=> u <= userlist[hi_id-1]
        const int ul_lo = (lo_id > 0) ? userlist[lo_id - 1] : INT_MIN;
        const int ul_hi = userlist[hi_id - 1];

        if (cc > 0) {
            // Monotonic counter: stale-low just causes a harmless atomic;
            // read >= n_chunks can only under-report => truly exhausted.
            if (t == 0) s_skip = (*(volatile int*)&claim[c * CLAIM_STRIDE] >= n_chunks);
            __syncthreads();
            const int skip = s_skip;
            __syncthreads();          // all reads done before next write
            if (skip) continue;
        }

        for (;;) {
            if (t == 0) {
                s_j     = atomicAdd(&claim[c * CLAIM_STRIDE], 1);
                q_count = 0;
            }
            __syncthreads();
            const int j = s_j;        // block-uniform
            if (j >= n_chunks) break; // uniform break; post-loop barrier orders s_j
            const int e0 = j * ELEMS_PER_BLOCK;

            // ---- Phase A: scan chunk, queue in-range elements ----
            const int b0 = e0 + t * 4;          // elements [e0,     e0+1024)
            const int b1 = e0 + 1024 + t * 4;   // elements [e0+1024, e0+2048)
            int  u[8];
            bool valid[8];
            if (e0 + ELEMS_PER_BLOCK <= n_elem) {
                i32x4 xa, xb;
                load_stream_2xi4(x + b0, x + b1, xa, xb);
                u[0] = xa.x; u[1] = xa.y; u[2] = xa.z; u[3] = xa.w;
                u[4] = xb.x; u[5] = xb.y; u[6] = xb.z; u[7] = xb.w;
#pragma unroll
                for (int k = 0; k < 8; ++k) valid[k] = true;
            } else {
#pragma unroll
                for (int k = 0; k < 4; ++k) {
                    valid[k]     = (b0 + k) < n_elem;
                    u[k]         = valid[k]     ? x[b0 + k] : 0;
                    valid[4 + k] = (b1 + k) < n_elem;
                    u[4 + k]     = valid[4 + k] ? x[b1 + k] : 0;
                }
            }
#pragma unroll
            for (int k = 0; k < 8; ++k) {
                const int  ge   = (k < 4) ? (b0 + k) : (b1 + k - 4);
                const bool flag = valid[k]
                                  && (lo_id == 0 || u[k] > ul_lo)
                                  && (u[k] <= ul_hi);
                int id = 0;
                if (flag) {                              // probe only in-range
                    int g = 1 + (u[k] - v1);             // interpolation probe
                    bool hit = (g >= 1 && g < n_user) && (userlist[g] == u[k]);
                    if (!hit) {                          // lower_bound fallback
                        int lo = 0, hi = n_user;
                        while (lo < hi) {
                            const int mid = (lo + hi) >> 1;
                            if (userlist[mid] < u[k]) lo = mid + 1;
                            else                      hi = mid;
                        }
                        g = lo;
                    }
                    id = g;
                }
                const unsigned long long m = __ballot(flag);
                if (m) {
                    int pos = 0;
                    if (lane == 0) pos = atomicAdd(&q_count, __popcll(m));
                    pos = __shfl(pos, 0);
                    pos += __popcll(m & ((1ull << lane) - 1ull));
                    if (flag) {
                        q_id[pos] = id;
                        q_ge[pos] = ge;
                    }
                }
            }
            __syncthreads();

            // ---- Phase B: wave-cooperative row copy, 4-deep MLP ----
            // Each lane handles entries i, i+16, i+32, i+48: four INDEPENDENT
            // gather loads issue before the first store needs its data.
            const int count = q_count;
            int i = wave * 4 + eslot;
            for (; i + 48 < count; i += 64) {
                const int id0 = q_id[i];      const int g0 = q_ge[i];
                const int id1 = q_id[i + 16]; const int g1 = q_ge[i + 16];
                const int id2 = q_id[i + 32]; const int g2 = q_ge[i + 32];
                const int id3 = q_id[i + 48]; const int g3 = q_ge[i + 48];
                const f32x4 r0 = emb4[(size_t)id0 * V4_PER_ROW + sub];
                const f32x4 r1 = emb4[(size_t)id1 * V4_PER_ROW + sub];
                const f32x4 r2 = emb4[(size_t)id2 * V4_PER_ROW + sub];
                const f32x4 r3 = emb4[(size_t)id3 * V4_PER_ROW + sub];
                store_nt_f4(&out4[(size_t)g0 * V4_PER_ROW + sub], r0);
                store_nt_f4(&out4[(size_t)g1 * V4_PER_ROW + sub], r1);
                store_nt_f4(&out4[(size_t)g2 * V4_PER_ROW + sub], r2);
                store_nt_f4(&out4[(size_t)g3 * V4_PER_ROW + sub], r3);
            }
            for (; i < count; i += 16) {
                const int id = q_id[i];
                const int ge = q_ge[i];
                const f32x4 row = emb4[(size_t)id * V4_PER_ROW + sub];
                store_nt_f4(&out4[(size_t)ge * V4_PER_ROW + sub], row);
            }
            __syncthreads();   // LDS + s_j reuse safety before next claim
        }
        __syncthreads();       // orders last s_j read before next range writes
    }
}

extern "C" void kernel_launch(void* const* d_in, const int* in_sizes, int n_in,
                              void* d_out, int out_size, void* d_ws, size_t ws_size,
                              hipStream_t stream) {
    const int*   x        = (const int*)d_in[0];    // [BATCH*HIST] indices
    const int*   userlist = (const int*)d_in[1];    // [USR_SIZE+1] sorted ids
    const float* emb      = (const float*)d_in[2];  // [USR_SIZE+1, 64]
    float*       out      = (float*)d_out;          // [BATCH*HIST, 64]

    const int n_elem = in_sizes[0];                 // 819200
    const int n_user = in_sizes[1];                 // 100001

    const int chunks = (n_elem + ELEMS_PER_BLOCK - 1) / ELEMS_PER_BLOCK;  // 400
    const int blocks = chunks * NXCD;                                     // 3200

    // Zero the padded claim counters (capture-safe async op on stream).
    hipMemsetAsync(d_ws, 0, NXCD * CLAIM_STRIDE * sizeof(int), stream);
    usr_emb_gather<<<blocks, 256, 0, stream>>>(x, userlist, n_user, emb, out,
                                               n_elem, chunks, (int*)d_ws);
}